// Round 10
// baseline (130.949 us; speedup 1.0000x reference)
//
#include <hip/hip_runtime.h>
#include <hip/hip_bf16.h>

// Chamfer distance, B=16, N=M=4096, D=3, fp32 — one-pass MFMA, both mins.
// Round-10: r4 VERBATIM main + fused per-batch last-block fold (4->3
// dispatches; tests the dispatch-overhead hypothesis).
//
// Evidence ledger (rounds 0-9):
//  * r4 = best (78.67us): 1024 blocks (q2 x b16 x strip32) x 256thr,
//    128 rows x 2048 cols, dbuf staging, rm[16]/wave (SPILL RULE: one
//    row-group, no in-loop shfl/divergence), 40KB LDS -> 4 blk/CU,
//    512KB atomicMin ws planes.
//  * Alternatives all lost: plain-store 8.5MB merge (r9: +4.7), 1-block
//    finish (r5/r6: +20), in-loop shfl+divergent atomics (r7: spill),
//    multi-row-group accumulators (r1/r2/r5: spill).
//  * Unexplained residual: modeled main ~12-15us vs inferred ~27-31us and
//    chain ~38.7us. This round removes the finish dispatch + its launch
//    gap; main loop untouched.
// Fold protocol: block merges -> threadfence (release) -> per-batch counter
// (0xFF-init, 64 bumps, last sees old==62) -> last block folds its batch's
// 8192 cells with coherent atomicAdd(p,0) reads -> atomicAdd(out).
// 3 dispatches: memset out 4B, memset ws 512KB+64B, main.

#define BATCH   16
#define NPTS    4096
#define NSTRIPS 32                 // 128 rows per block
#define NQ      2                  // col halves
#define COLS_PB 2048
#define CHUNKC  512
#define NCHUNKS (COLS_PB / CHUNKC) // 4
#define NSTEP   (CHUNKC / 64)      // 8

typedef __attribute__((ext_vector_type(8)))  short short8;
typedef __attribute__((ext_vector_type(16))) float float16;

union U4S8 { uint4 u; short8 s; };

__device__ inline unsigned int bfb(float v) {
    __hip_bfloat16 h = __float2bfloat16(v);
    unsigned short u; __builtin_memcpy(&u, &h, 2);
    return (unsigned int)u;
}
__device__ inline float bff(float v) { return __bfloat162float(__float2bfloat16(v)); }

#define ONEB 0x3F80u

// A (query) slots: [xh yh zh xh yh zh xl yl | zl fh fl 1 1 0 0 0]
__device__ inline void buildA(float x, float y, float z, uint4& w0, uint4& w1) {
    float xhf = bff(x), yhf = bff(y), zhf = bff(z);
    float f = fmaf(x, x, fmaf(y, y, z * z));
    float fhf = bff(f);
    unsigned xh = bfb(xhf), yh = bfb(yhf), zh = bfb(zhf);
    unsigned xl = bfb(x - xhf), yl = bfb(y - yhf), zl = bfb(z - zhf);
    unsigned fh = bfb(fhf), fl = bfb(f - fhf);
    w0 = make_uint4(xh | (yh << 16), zh | (xh << 16),
                    yh | (zh << 16), xl | (yl << 16));
    w1 = make_uint4(zl | (fh << 16), fl | (ONEB << 16), ONEB, 0u);
}

// B (target) slots: [-2xh -2yh -2zh -2xl -2yl -2zl -2xh -2yh | -2zh 1 1 fh fl 0 0 0]
__device__ inline void buildB(float x, float y, float z, uint4& w0, uint4& w1) {
    float xhf = bff(x), yhf = bff(y), zhf = bff(z);
    float f = fmaf(x, x, fmaf(y, y, z * z));
    float fhf = bff(f);
    unsigned a = bfb(-2.0f * xhf), b = bfb(-2.0f * yhf), c = bfb(-2.0f * zhf);
    unsigned d = bfb(-2.0f * (x - xhf)), e = bfb(-2.0f * (y - yhf)),
             g = bfb(-2.0f * (z - zhf));
    unsigned fh = bfb(fhf), fl = bfb(f - fhf);
    w0 = make_uint4(a | (b << 16), c | (d << 16),
                    e | (g << 16), a | (b << 16));
    w1 = make_uint4(c | (ONEB << 16), ONEB | (fh << 16), fl, 0u);
}

// min over the 16 regs (this half's 16 rows) of one 32x32 MFMA result.
__device__ inline float tree16(const float16& a) {
    float m0 = fminf(fminf(a[0],  a[1]),  a[2]);    // v_min3
    float m1 = fminf(fminf(a[3],  a[4]),  a[5]);
    float m2 = fminf(fminf(a[6],  a[7]),  a[8]);
    float m3 = fminf(fminf(a[9],  a[10]), a[11]);
    float m4 = fminf(fminf(a[12], a[13]), a[14]);
    float p0 = fminf(fminf(m0, m1), a[15]);
    float p1 = fminf(fminf(m2, m3), m4);
    return fminf(p0, p1);
}

__global__ __launch_bounds__(256, 4) void chamfer_main(
    const float* __restrict__ src, const float* __restrict__ tgt,
    unsigned* __restrict__ wsC, unsigned* __restrict__ wsR,
    unsigned* __restrict__ done, float* __restrict__ out)
{
    __shared__ uint4    sbuf[2][2][CHUNKC];   // [buf][half][pt] = 32 KB
    __shared__ unsigned colpart[COLS_PB];     // 8 KB; LDS total 40KB -> 4/CU

    int blk = blockIdx.x;
    const int strip = blk & (NSTRIPS - 1); blk >>= 5;
    const int b     = blk & 15;            blk >>= 4;
    const int q     = blk;                 // col half 0/1
    const int qoff  = q * COLS_PB;

    const int t    = threadIdx.x;
    const int lane = t & 63;
    const int w    = t >> 6;
    const int h    = lane >> 5;
    const int l5   = lane & 31;

    const float* Araw = src + (size_t)b * NPTS * 3;   // rows (queries)
    const float* Braw = tgt + (size_t)b * NPTS * 3;   // cols (targets)

    // A fragment: one 32-row group per wave (128 rows per block). SPILL RULE.
    short8 afr;
    {
        int row = strip * 128 + w * 32 + l5;
        uint4 w0, w1;
        buildA(Araw[3 * row], Araw[3 * row + 1], Araw[3 * row + 2], w0, w1);
        U4S8 tt; tt.u = h ? w1 : w0;
        afr = tt.s;
    }

    // init block-local col-min plane (8 entries per thread)
#pragma unroll
    for (int i = 0; i < COLS_PB / 256; i++) colpart[t + i * 256] = 0xFFFFFFFFu;

    // Pipelined B staging: raw loads (regs) early, convert + ds_write late.
    float nx[2][3];
    auto loadRaw = [&](int c) {
#pragma unroll
        for (int k = 0; k < 2; k++) {
            int p = qoff + c * CHUNKC + t + k * 256;
            nx[k][0] = Braw[3 * p + 0];
            nx[k][1] = Braw[3 * p + 1];
            nx[k][2] = Braw[3 * p + 2];
        }
    };
    auto convertWrite = [&](int bi) {
#pragma unroll
        for (int k = 0; k < 2; k++) {
            int lp = t + k * 256;
            uint4 w0, w1;
            buildB(nx[k][0], nx[k][1], nx[k][2], w0, w1);
            sbuf[bi][0][lp] = w0;
            sbuf[bi][1][lp] = w1;
        }
    };

    const float16 z16 = {0.f,0.f,0.f,0.f,0.f,0.f,0.f,0.f,
                         0.f,0.f,0.f,0.f,0.f,0.f,0.f,0.f};
    float rm[16];
#pragma unroll
    for (int r = 0; r < 16; r++) rm[r] = 1e30f;

    loadRaw(0);
    convertWrite(0);
    for (int c = 0; c < NCHUNKS; c++) {
        __syncthreads();              // buf[c&1] written; prior-iter reads done
        if (c + 1 < NCHUNKS) loadRaw(c + 1);   // issue, don't wait
        const int bi = c & 1;

        U4S8 c0, c1, n0, n1;
        c0.u = sbuf[bi][h][l5];
        c1.u = sbuf[bi][h][32 + l5];
#pragma unroll 4
        for (int j = 0; j < NSTEP; j++) {
            int nj = (j + 1) & (NSTEP - 1);        // wrap re-read: harmless
            n0.u = sbuf[bi][h][nj * 64 + l5];
            n1.u = sbuf[bi][h][nj * 64 + 32 + l5];
            float16 a0 = __builtin_amdgcn_mfma_f32_32x32x16_bf16(afr, c0.s, z16, 0, 0, 0);
            float16 a1 = __builtin_amdgcn_mfma_f32_32x32x16_bf16(afr, c1.s, z16, 0, 0, 0);
#pragma unroll
            for (int r = 0; r < 16; r++)
                rm[r] = fminf(fminf(a0[r], a1[r]), rm[r]);     // v_min3
            // col-mins over this half's 16 rows; 64-lane LDS atomicMin
            // merges halves and waves (r4-identical).
            float cm0 = tree16(a0);
            float cm1 = tree16(a1);
            const int col = c * CHUNKC + j * 64 + l5;
            atomicMin(&colpart[col],      __float_as_uint(fmaxf(cm0, 0.0f)));
            atomicMin(&colpart[col + 32], __float_as_uint(fmaxf(cm1, 0.0f)));
            c0 = n0; c1 = n1;
        }
        if (c + 1 < NCHUNKS) convertWrite((c + 1) & 1);      // vmcnt hidden
    }

    __syncthreads();                       // all col atomics visible

    // merge block-local col-mins into the global plane (8 per thread)
#pragma unroll
    for (int i = 0; i < COLS_PB / 256; i++) {
        const int idx = t + i * 256;
        atomicMin(&wsC[(size_t)b * NPTS + qoff + idx], colpart[idx]);
    }

    // Row-min partial (this block's 2048 cols): fold 32 col-slots across
    // lanes (masks 1..16; h-halves hold disjoint row sets -> no mask 32).
#pragma unroll
    for (int mask = 1; mask <= 16; mask <<= 1)
#pragma unroll
        for (int r = 0; r < 16; r++)
            rm[r] = fminf(rm[r], __shfl_xor(rm[r], mask, 64));

    // transpose via LDS (reuse colpart[0:128) after its merge-reads), then
    // coalesced clamped atomicMin into wsR.
    __syncthreads();                 // colpart merge reads done
    if (l5 == 0) {
#pragma unroll
        for (int r = 0; r < 16; r++) {
            const int row = w * 32 + (r & 3) + 8 * (r >> 2) + 4 * h;
            colpart[row] = __float_as_uint(fmaxf(rm[r], 0.0f));
        }
    }
    __syncthreads();
    if (t < 128)
        atomicMin(&wsR[(size_t)b * NPTS + strip * 128 + t], colpart[t]);

    // ---------------- fused finish: last block of this batch folds ------
    __threadfence();                 // release this thread's global atomics
    __syncthreads();                 // whole block fenced; colpart reusable
    if (t == 0) {
        unsigned old = atomicAdd(&done[b], 1u);   // init 0xFFFFFFFF; 64 bumps
        colpart[0] = (old == 62u) ? 1u : 0u;      // 64th bumper sees 62
    }
    __syncthreads();
    if (colpart[0]) {
        // fold batch b: 4096 col-min + 4096 row-min cells, coherent reads.
        unsigned* cbase = wsC + (size_t)b * NPTS;
        unsigned* rbase = wsR + (size_t)b * NPTS;
        float v = 0.0f;
#pragma unroll
        for (int i = 0; i < 16; i++) {
            v += __uint_as_float(atomicAdd(&cbase[t + i * 256], 0u));
            v += __uint_as_float(atomicAdd(&rbase[t + i * 256], 0u));
        }
#pragma unroll
        for (int mask = 1; mask <= 32; mask <<= 1) v += __shfl_xor(v, mask, 64);
        if (lane == 0) colpart[1 + w] = __float_as_uint(v);
        __syncthreads();
        if (t == 0) {
            float s = __uint_as_float(colpart[1]) + __uint_as_float(colpart[2])
                    + __uint_as_float(colpart[3]) + __uint_as_float(colpart[4]);
            atomicAdd(out, s * (1.0f / (float)NPTS));
        }
    }
}

// ---------------------------------------------------------------- launch
extern "C" void kernel_launch(void* const* d_in, const int* in_sizes, int n_in,
                              void* d_out, int out_size, void* d_ws, size_t ws_size,
                              hipStream_t stream)
{
    const float* src = (const float*)d_in[0];
    const float* tgt = (const float*)d_in[1];
    float* out = (float*)d_out;

    // ws: [wsC 256KB][wsR 256KB][done 64B] — all 0xFF-init by one memset.
    unsigned* wsC  = (unsigned*)d_ws;
    unsigned* wsR  = wsC + (size_t)BATCH * NPTS;
    unsigned* done = wsR + (size_t)BATCH * NPTS;

    hipMemsetAsync(out, 0, sizeof(float), stream);
    hipMemsetAsync(d_ws, 0xFF,
                   (size_t)2 * BATCH * NPTS * sizeof(unsigned) + 64, stream);
    chamfer_main<<<NQ * BATCH * NSTRIPS, 256, 0, stream>>>(src, tgt, wsC, wsR,
                                                           done, out);
}

// Round 11
// 84.934 us; speedup vs baseline: 1.5418x; 1.5418x over previous
//
#include <hip/hip_runtime.h>
#include <hip/hip_bf16.h>

// Chamfer distance, B=16, N=M=4096, D=3, fp32 — one-pass MFMA, both mins.
// Round-11: r0's 4-MFMA inner structure + (256,2) register budget, one-pass.
//
// Evidence ledger (rounds 0-10):
//  * r0 (two-pass, 4 MFMA/step, rm[2][16], launch_bounds(256,2)) ran BOTH
//    directions in ~37us main: the most work-efficient loop measured.
//  * One-pass at tight caps starved or spilled: (256,4)+2MFMA = ~30us main
//    (r4, best total 78.7); 4-MFMA at 84/128-VGPR caps spilled (r2/r5).
//  * r10 proved epilogue code can perturb regalloc (VGPR 64) and cause
//    L2-resident scratch spill invisible to FETCH/WRITE. Health check:
//    VGPR_Count must be ~150-220 here, NOT 64.
//  * THIS round: the untested matrix cell — one-pass, 4-MFMA steps, at
//    (256,2) so the allocator has r0's 256-VGPR headroom.
// Grid: q(2) x b(16) x strip(16) = 512 blocks x 256 thr; 256 rows x 2048
// cols per block; CHUNKC=1024 dbuf (64KB) + colpart 8KB = 72KB -> 2 blk/CU.
//   row-min -> cham_x : rm[2][16] accum -> epilogue shfl fold -> transpose
//                       via colpart -> clamped atomicMin wsR (r4-verbatim).
//   col-min -> cham_y : min16pair trees -> 64-lane LDS atomicMin colpart ->
//                       block-end global atomicMin wsC (r4-verbatim).
// finish: 32 blocks sum both 256KB planes -> atomicAdd out (r4-verbatim).
// 4 dispatches: memset out, memset ws 512KB, main, finish.

#define BATCH   16
#define NPTS    4096
#define NSTRIPS 16                 // 256 rows per block
#define NQ      2                  // col halves
#define COLS_PB 2048
#define CHUNKC  1024
#define NCHUNKS (COLS_PB / CHUNKC) // 2
#define NSTEP   (CHUNKC / 64)      // 16

typedef __attribute__((ext_vector_type(8)))  short short8;
typedef __attribute__((ext_vector_type(16))) float float16;

union U4S8 { uint4 u; short8 s; };

__device__ inline unsigned int bfb(float v) {
    __hip_bfloat16 h = __float2bfloat16(v);
    unsigned short u; __builtin_memcpy(&u, &h, 2);
    return (unsigned int)u;
}
__device__ inline float bff(float v) { return __bfloat162float(__float2bfloat16(v)); }

#define ONEB 0x3F80u

// A (query) slots: [xh yh zh xh yh zh xl yl | zl fh fl 1 1 0 0 0]
__device__ inline void buildA(float x, float y, float z, uint4& w0, uint4& w1) {
    float xhf = bff(x), yhf = bff(y), zhf = bff(z);
    float f = fmaf(x, x, fmaf(y, y, z * z));
    float fhf = bff(f);
    unsigned xh = bfb(xhf), yh = bfb(yhf), zh = bfb(zhf);
    unsigned xl = bfb(x - xhf), yl = bfb(y - yhf), zl = bfb(z - zhf);
    unsigned fh = bfb(fhf), fl = bfb(f - fhf);
    w0 = make_uint4(xh | (yh << 16), zh | (xh << 16),
                    yh | (zh << 16), xl | (yl << 16));
    w1 = make_uint4(zl | (fh << 16), fl | (ONEB << 16), ONEB, 0u);
}

// B (target) slots: [-2xh -2yh -2zh -2xl -2yl -2zl -2xh -2yh | -2zh 1 1 fh fl 0 0 0]
__device__ inline void buildB(float x, float y, float z, uint4& w0, uint4& w1) {
    float xhf = bff(x), yhf = bff(y), zhf = bff(z);
    float f = fmaf(x, x, fmaf(y, y, z * z));
    float fhf = bff(f);
    unsigned a = bfb(-2.0f * xhf), b = bfb(-2.0f * yhf), c = bfb(-2.0f * zhf);
    unsigned d = bfb(-2.0f * (x - xhf)), e = bfb(-2.0f * (y - yhf)),
             g = bfb(-2.0f * (z - zhf));
    unsigned fh = bfb(fhf), fl = bfb(f - fhf);
    w0 = make_uint4(a | (b << 16), c | (d << 16),
                    e | (g << 16), a | (b << 16));
    w1 = make_uint4(c | (ONEB << 16), ONEB | (fh << 16), fl, 0u);
}

// elementwise min of two MFMA results, then min3 tree over the 16 regs
// (= min over the 32 rows covered by this half across both row-groups).
__device__ inline float min16pair(const float16& a, const float16& b) {
    float t0  = fminf(a[0],  b[0]),  t1  = fminf(a[1],  b[1]);
    float t2  = fminf(a[2],  b[2]),  t3  = fminf(a[3],  b[3]);
    float t4  = fminf(a[4],  b[4]),  t5  = fminf(a[5],  b[5]);
    float t6  = fminf(a[6],  b[6]),  t7  = fminf(a[7],  b[7]);
    float t8  = fminf(a[8],  b[8]),  t9  = fminf(a[9],  b[9]);
    float t10 = fminf(a[10], b[10]), t11 = fminf(a[11], b[11]);
    float t12 = fminf(a[12], b[12]), t13 = fminf(a[13], b[13]);
    float t14 = fminf(a[14], b[14]), t15 = fminf(a[15], b[15]);
    float m0 = fminf(fminf(t0,  t1),  t2);    // v_min3
    float m1 = fminf(fminf(t3,  t4),  t5);
    float m2 = fminf(fminf(t6,  t7),  t8);
    float m3 = fminf(fminf(t9,  t10), t11);
    float m4 = fminf(fminf(t12, t13), t14);
    float p0 = fminf(fminf(m0, m1), t15);
    float p1 = fminf(fminf(m2, m3), m4);
    return fminf(p0, p1);
}

__global__ __launch_bounds__(256, 2) void chamfer_main(
    const float* __restrict__ src, const float* __restrict__ tgt,
    unsigned* __restrict__ wsC, unsigned* __restrict__ wsR)
{
    __shared__ uint4    sbuf[2][2][CHUNKC];   // [buf][half][pt] = 64 KB
    __shared__ unsigned colpart[COLS_PB];     // 8 KB; LDS 72KB -> 2 blk/CU

    int blk = blockIdx.x;
    const int strip = blk & (NSTRIPS - 1); blk >>= 4;
    const int b     = blk & 15;            blk >>= 4;
    const int q     = blk;                 // col half 0/1
    const int qoff  = q * COLS_PB;

    const int t    = threadIdx.x;
    const int lane = t & 63;
    const int w    = t >> 6;
    const int h    = lane >> 5;
    const int l5   = lane & 31;

    const float* Araw = src + (size_t)b * NPTS * 3;   // rows (queries)
    const float* Braw = tgt + (size_t)b * NPTS * 3;   // cols (targets)

    // A fragments: 2 row-groups of 32 rows per wave (256 rows per block) —
    // r0 mapping, safe at the (256,2) register budget.
    short8 afr[2];
#pragma unroll
    for (int g = 0; g < 2; g++) {
        int row = strip * 256 + g * 128 + w * 32 + l5;
        uint4 w0, w1;
        buildA(Araw[3 * row], Araw[3 * row + 1], Araw[3 * row + 2], w0, w1);
        U4S8 tt; tt.u = h ? w1 : w0;
        afr[g] = tt.s;
    }

    // init block-local col-min plane (8 entries per thread)
#pragma unroll
    for (int i = 0; i < COLS_PB / 256; i++) colpart[t + i * 256] = 0xFFFFFFFFu;

    // Pipelined B staging (r0-verbatim): raw loads early, convert late.
    float nx[4][3];
    auto loadRaw = [&](int c) {
#pragma unroll
        for (int k = 0; k < 4; k++) {
            int p = qoff + c * CHUNKC + t + k * 256;
            nx[k][0] = Braw[3 * p + 0];
            nx[k][1] = Braw[3 * p + 1];
            nx[k][2] = Braw[3 * p + 2];
        }
    };
    auto convertWrite = [&](int bi) {
#pragma unroll
        for (int k = 0; k < 4; k++) {
            int lp = t + k * 256;
            uint4 w0, w1;
            buildB(nx[k][0], nx[k][1], nx[k][2], w0, w1);
            sbuf[bi][0][lp] = w0;
            sbuf[bi][1][lp] = w1;
        }
    };

    const float16 z16 = {0.f,0.f,0.f,0.f,0.f,0.f,0.f,0.f,
                         0.f,0.f,0.f,0.f,0.f,0.f,0.f,0.f};
    float rm[2][16];
#pragma unroll
    for (int g = 0; g < 2; g++)
#pragma unroll
        for (int r = 0; r < 16; r++) rm[g][r] = 1e30f;

    loadRaw(0);
    convertWrite(0);
    for (int c = 0; c < NCHUNKS; c++) {
        __syncthreads();              // buf[c&1] written; prior-iter reads done
        if (c + 1 < NCHUNKS) loadRaw(c + 1);   // issue, don't wait
        const int bi = c & 1;

        // r0's software-pipelined step: prefetch next frags, 4 MFMAs
        // back-to-back (max MFMA->readback distance), folds, col trees.
        U4S8 c0, c1, n0, n1;
        c0.u = sbuf[bi][h][l5];
        c1.u = sbuf[bi][h][32 + l5];
#pragma unroll 4
        for (int j2 = 0; j2 < NSTEP; j2++) {
            int nj = (j2 + 1) & (NSTEP - 1);       // wrap re-read: harmless
            n0.u = sbuf[bi][h][nj * 64 + l5];
            n1.u = sbuf[bi][h][nj * 64 + 32 + l5];
            float16 a00 = __builtin_amdgcn_mfma_f32_32x32x16_bf16(afr[0], c0.s, z16, 0, 0, 0);
            float16 a01 = __builtin_amdgcn_mfma_f32_32x32x16_bf16(afr[0], c1.s, z16, 0, 0, 0);
            float16 a10 = __builtin_amdgcn_mfma_f32_32x32x16_bf16(afr[1], c0.s, z16, 0, 0, 0);
            float16 a11 = __builtin_amdgcn_mfma_f32_32x32x16_bf16(afr[1], c1.s, z16, 0, 0, 0);
#pragma unroll
            for (int r = 0; r < 16; r++) {
                rm[0][r] = fminf(fminf(a00[r], a01[r]), rm[0][r]);   // v_min3
                rm[1][r] = fminf(fminf(a10[r], a11[r]), rm[1][r]);
            }
            // col-mins over all 32 rows of this half; 64-lane LDS atomicMin
            // merges halves and waves (r3/r4-proven pattern).
            float cm0 = min16pair(a00, a10);
            float cm1 = min16pair(a01, a11);
            const int col = c * CHUNKC + j2 * 64 + l5;
            atomicMin(&colpart[col],      __float_as_uint(fmaxf(cm0, 0.0f)));
            atomicMin(&colpart[col + 32], __float_as_uint(fmaxf(cm1, 0.0f)));
            c0 = n0; c1 = n1;
        }
        if (c + 1 < NCHUNKS) convertWrite((c + 1) & 1);      // vmcnt hidden
    }

    __syncthreads();                       // all col atomics visible

    // merge block-local col-mins into the global plane (8 per thread)
#pragma unroll
    for (int i = 0; i < COLS_PB / 256; i++) {
        const int idx = t + i * 256;
        atomicMin(&wsC[(size_t)b * NPTS + qoff + idx], colpart[idx]);
    }

    // Row-min partial (this block's 2048 cols): epilogue shfl fold
    // (masks 1..16; h-halves hold disjoint row sets -> no mask 32).
#pragma unroll
    for (int mask = 1; mask <= 16; mask <<= 1)
#pragma unroll
        for (int g = 0; g < 2; g++)
#pragma unroll
            for (int r = 0; r < 16; r++)
                rm[g][r] = fminf(rm[g][r], __shfl_xor(rm[g][r], mask, 64));

    // transpose via colpart (dead after merge reads), coalesced atomicMin.
    __syncthreads();                 // colpart merge reads done
    if (l5 == 0) {
#pragma unroll
        for (int g = 0; g < 2; g++)
#pragma unroll
            for (int r = 0; r < 16; r++) {
                const int row = g * 128 + w * 32 + (r & 3) + 8 * (r >> 2) + 4 * h;
                colpart[row] = __float_as_uint(fmaxf(rm[g][r], 0.0f));
            }
    }
    __syncthreads();
    atomicMin(&wsR[(size_t)b * NPTS + strip * 256 + t], colpart[t]);
}

// ---- finish: 32 blocks (XCD-spread) sum both planes -> atomicAdd out
__global__ __launch_bounds__(256) void finish_reduce(
    const unsigned* __restrict__ ws, float* __restrict__ out)
{
    __shared__ float wsum[4];
    const int tg = blockIdx.x * 256 + threadIdx.x;   // 8192 threads
    float v = 0.0f;
#pragma unroll
    for (int i = 0; i < 16; i++)                     // 131072 cells total
        v += __uint_as_float(ws[tg + i * 8192]);
#pragma unroll
    for (int mask = 1; mask <= 32; mask <<= 1) v += __shfl_xor(v, mask, 64);
    if ((threadIdx.x & 63) == 0) wsum[threadIdx.x >> 6] = v;
    __syncthreads();
    if (threadIdx.x == 0)
        atomicAdd(out, (wsum[0] + wsum[1] + wsum[2] + wsum[3]) * (1.0f / (float)NPTS));
}

// ---------------------------------------------------------------- launch
extern "C" void kernel_launch(void* const* d_in, const int* in_sizes, int n_in,
                              void* d_out, int out_size, void* d_ws, size_t ws_size,
                              hipStream_t stream)
{
    const float* src = (const float*)d_in[0];
    const float* tgt = (const float*)d_in[1];
    float* out = (float*)d_out;
    unsigned* wsC = (unsigned*)d_ws;                      // 256 KB
    unsigned* wsR = wsC + (size_t)BATCH * NPTS;           // 256 KB

    hipMemsetAsync(out, 0, sizeof(float), stream);
    hipMemsetAsync(d_ws, 0xFF, (size_t)2 * BATCH * NPTS * sizeof(unsigned), stream);
    chamfer_main <<<NQ * BATCH * NSTRIPS, 256, 0, stream>>>(src, tgt, wsC, wsR);
    finish_reduce<<<32, 256, 0, stream>>>((const unsigned*)d_ws, out);
}